// Round 1
// baseline (256.431 us; speedup 1.0000x reference)
//
#include <hip/hip_runtime.h>
#include <math.h>

#define N_T   2000
#define CHUNK 32   // timesteps per lane; 64 lanes * 32 = 2048 >= 2000

// One wave (64 lanes) per trial. Linear-recurrence wave-scan:
//   e[t+1] = decay*e[t] + u[t]  ==> per-lane chunk is affine map (A,B),
//   compose maps across lanes with __shfl_up (low lane applied first).
__global__ __launch_bounds__(256) void ddm_kernel(
    const float* __restrict__ stim,
    const float* __restrict__ noise,
    const float* __restrict__ a_p,
    const float* __restrict__ z_p,
    const float* __restrict__ gain_p,
    const float* __restrict__ off_p,
    const float* __restrict__ beta_p,
    float* __restrict__ out,
    int n_trials)
{
    const int wave  = threadIdx.x >> 6;
    const int lane  = threadIdx.x & 63;
    const int trial = blockIdx.x * 4 + wave;
    if (trial >= n_trials) return;

    const float a    = *a_p;
    const float z    = *z_p;
    const float gain = *gain_p;
    const float offs = *off_p;
    const float beta = *beta_p;

    const float DT    = 0.001f;
    const float LEAK  = 0.01f;
    const float sp    = z * a;                  // starting point
    const float decay = 1.0f - LEAK * DT;       // 0.99999
    const float C1    = gain * DT;
    const float C2    = sqrtf(1.0f * DT);       // sqrt(VARIANCE*DT)
    const float C3    = offs * DT + LEAK * sp * DT;

    const float* srow = stim  + (size_t)trial * N_T;
    const float* nrow = noise + (size_t)trial * N_T;
    const int t0 = lane * CHUNK;

    // ---- load chunk, form u ----
    float u[CHUNK];
#pragma unroll
    for (int m = 0; m < CHUNK / 4; ++m) {
        const int t = t0 + 4 * m;
        float4 s4 = make_float4(0.f, 0.f, 0.f, 0.f);
        float4 n4 = make_float4(0.f, 0.f, 0.f, 0.f);
        if (t < N_T) {                 // N_T % 4 == 0: group fully valid or not
            s4 = *(const float4*)(srow + t);
            n4 = *(const float4*)(nrow + t);
        }
        u[4 * m + 0] = C1 * s4.x + C2 * n4.x + C3;
        u[4 * m + 1] = C1 * s4.y + C2 * n4.y + C3;
        u[4 * m + 2] = C1 * s4.z + C2 * n4.z + C3;
        u[4 * m + 3] = C1 * s4.w + C2 * n4.w + C3;
    }

    // ---- per-lane affine reduction: e_out = A*e_in + B over the chunk ----
    float B = 0.f;
#pragma unroll
    for (int k = 0; k < CHUNK; ++k) B = decay * B + u[k];
    const float d2 = decay * decay;
    const float d4 = d2 * d2, d8 = d4 * d4, d16 = d8 * d8;
    float A = d16 * d16;                        // decay^32

    // ---- inclusive wave scan of affine maps (lane order = time order) ----
#pragma unroll
    for (int off = 1; off < 64; off <<= 1) {
        const float A_prev = __shfl_up(A, off, 64);
        const float B_prev = __shfl_up(B, off, 64);
        if (lane >= off) {
            B = A * B_prev + B;   // combine: m_cur ∘ m_prev  (B uses old A)
            A = A * A_prev;
        }
    }

    // entry evidence for this lane's chunk = scan result of previous lane
    const float A_inc = __shfl_up(A, 1, 64);
    const float B_inc = __shfl_up(B, 1, 64);
    float e = (lane == 0) ? sp : (A_inc * sp + B_inc);

    // ---- replay chunk, emit dv / h1 / h0 ----
    float* dv_out = out;
    float* h1_out = out + (size_t)n_trials * N_T;
    float* h0_out = out + 2 * (size_t)n_trials * N_T;
    const size_t row = (size_t)trial * N_T;

#pragma unroll
    for (int m = 0; m < CHUNK / 4; ++m) {
        const int tb = t0 + 4 * m;
        float4 dv4, h14, h04;
#pragma unroll
        for (int q = 0; q < 4; ++q) {
            const int t = tb + q;
            const float urg = (float)t * 0.01f;
            const float dv  = urg * (e - sp) + sp;
            const float h1  = 1.0f / (1.0f + __expf(-beta * (dv - a)));
            const float h0  = 1.0f / (1.0f + __expf(beta * dv));
            ((float*)&dv4)[q] = dv;
            ((float*)&h14)[q] = h1;
            ((float*)&h04)[q] = h0;
            e = decay * e + u[4 * m + q];       // advance recurrence
        }
        if (tb < N_T) {
            *(float4*)(dv_out + row + tb) = dv4;
            *(float4*)(h1_out + row + tb) = h14;
            *(float4*)(h0_out + row + tb) = h04;
        }
    }
}

extern "C" void kernel_launch(void* const* d_in, const int* in_sizes, int n_in,
                              void* d_out, int out_size, void* d_ws, size_t ws_size,
                              hipStream_t stream) {
    const float* stim  = (const float*)d_in[0];
    const float* noise = (const float*)d_in[1];
    const float* a_p   = (const float*)d_in[2];
    const float* z_p   = (const float*)d_in[3];
    const float* g_p   = (const float*)d_in[4];
    const float* o_p   = (const float*)d_in[5];
    const float* b_p   = (const float*)d_in[6];
    float* out = (float*)d_out;

    const int n_trials = in_sizes[0] / N_T;
    const int blocks = (n_trials + 3) / 4;   // 4 trials (waves) per block
    ddm_kernel<<<blocks, 256, 0, stream>>>(stim, noise, a_p, z_p, g_p, o_p, b_p,
                                           out, n_trials);
}

// Round 2
// 159.288 us; speedup vs baseline: 1.6099x; 1.6099x over previous
//
#include <hip/hip_runtime.h>
#include <math.h>

#define N_T   2000
#define NG    500     // float4 groups per trial (2000/4)
#define CHUNK 32      // timesteps per lane; 64*32 = 2048 >= 2000
#define WAVES 4       // waves (=trials) per block

// One wave per trial. Affine wave-scan for the linear recurrence
// e[t+1] = decay*e[t] + u[t]. All GLOBAL traffic is coalesced (lane i of a
// wave64 instr touches consecutive float4s -> 1KB/instr contiguous); the
// time-order chunk layout the scan needs lives only in LDS, with an XOR
// swizzle (p = lane*8 + (slot ^ (lane&7))) so both the coalesced side and
// the chunk side are bank-conflict-free (Latin square over bank quads).
__global__ __launch_bounds__(256) void ddm_kernel(
    const float* __restrict__ stim,
    const float* __restrict__ noise,
    const float* __restrict__ a_p,
    const float* __restrict__ z_p,
    const float* __restrict__ gain_p,
    const float* __restrict__ off_p,
    const float* __restrict__ beta_p,
    float* __restrict__ out,
    int n_trials)
{
    __shared__ float4 lbuf[WAVES][512];   // 32 KB/block

    const int wave  = threadIdx.x >> 6;
    const int lane  = threadIdx.x & 63;
    const int trial = blockIdx.x * WAVES + wave;   // n_trials % WAVES == 0

    const float a    = *a_p;
    const float z    = *z_p;
    const float gain = *gain_p;
    const float offs = *off_p;
    const float beta = *beta_p;

    const float DT    = 0.001f;
    const float LEAK  = 0.01f;
    const float sp    = z * a;
    const float decay = 1.0f - LEAK * DT;      // 0.99999
    const float C1    = gain * DT;
    const float C2    = sqrtf(1.0f * DT);      // sqrt(VARIANCE*DT)
    const float C3    = offs * DT + LEAK * sp * DT;

    const float* srow = stim  + (size_t)trial * N_T;
    const float* nrow = noise + (size_t)trial * N_T;

    // ---- phase 1: coalesced load, form u elementwise, scatter to LDS ----
#pragma unroll
    for (int j = 0; j < 8; ++j) {
        const int g = j * 64 + lane;           // global vec4 group in trial
        float4 u4 = make_float4(0.f, 0.f, 0.f, 0.f);
        if (g < NG) {
            const float4 s4 = *(const float4*)(srow + 4 * g);
            const float4 n4 = *(const float4*)(nrow + 4 * g);
            u4.x = C1 * s4.x + C2 * n4.x + C3;
            u4.y = C1 * s4.y + C2 * n4.y + C3;
            u4.z = C1 * s4.z + C2 * n4.z + C3;
            u4.w = C1 * s4.w + C2 * n4.w + C3;
        }
        const int lp = g >> 3;                 // owning lane (chunk order)
        const int sl = g & 7;                  // slot within that lane
        lbuf[wave][lp * 8 + (sl ^ (lp & 7))] = u4;
    }
    __syncthreads();

    // ---- phase 2: lane-private chunk read from LDS ----
    float u[CHUNK];
#pragma unroll
    for (int g = 0; g < 8; ++g) {
        const float4 u4 = lbuf[wave][lane * 8 + (g ^ (lane & 7))];
        u[4 * g + 0] = u4.x;
        u[4 * g + 1] = u4.y;
        u[4 * g + 2] = u4.z;
        u[4 * g + 3] = u4.w;
    }

    // ---- affine reduction over chunk: e_out = A*e_in + B ----
    float B = 0.f;
#pragma unroll
    for (int k = 0; k < CHUNK; ++k) B = decay * B + u[k];
    const float d2 = decay * decay;
    const float d4 = d2 * d2, d8 = d4 * d4, d16 = d8 * d8;
    float A = d16 * d16;                       // decay^32

    // ---- inclusive wave scan of affine maps ----
#pragma unroll
    for (int off = 1; off < 64; off <<= 1) {
        const float A_prev = __shfl_up(A, off, 64);
        const float B_prev = __shfl_up(B, off, 64);
        if (lane >= off) {
            B = A * B_prev + B;
            A = A * A_prev;
        }
    }
    const float A_inc = __shfl_up(A, 1, 64);
    const float B_inc = __shfl_up(B, 1, 64);
    float e = (lane == 0) ? sp : (A_inc * sp + B_inc);

    // ---- phase 3: replay chunk, write dv back to lane-private LDS slots ----
#pragma unroll
    for (int g = 0; g < 8; ++g) {
        float4 dv4;
#pragma unroll
        for (int q = 0; q < 4; ++q) {
            const int t  = lane * CHUNK + 4 * g + q;
            const float urg = (float)t * 0.01f;
            ((float*)&dv4)[q] = urg * (e - sp) + sp;
            e = decay * e + u[4 * g + q];
        }
        lbuf[wave][lane * 8 + (g ^ (lane & 7))] = dv4;   // same slots read above
    }
    __syncthreads();

    // ---- phase 4: coalesced gather from LDS, compute h1/h0, store all 3 ----
    float* dv_out = out;
    float* h1_out = out + (size_t)n_trials * N_T;
    float* h0_out = out + 2 * (size_t)n_trials * N_T;

#pragma unroll
    for (int j = 0; j < 8; ++j) {
        const int g = j * 64 + lane;
        if (g < NG) {
            const int lp = g >> 3;
            const int sl = g & 7;
            const float4 dv4 = lbuf[wave][lp * 8 + (sl ^ (lp & 7))];
            float4 h14, h04;
#pragma unroll
            for (int q = 0; q < 4; ++q) {
                const float dv = ((const float*)&dv4)[q];
                ((float*)&h14)[q] = 1.0f / (1.0f + __expf(-beta * (dv - a)));
                ((float*)&h04)[q] = 1.0f / (1.0f + __expf(beta * dv));
            }
            const size_t base = (size_t)trial * N_T + 4 * g;
            *(float4*)(dv_out + base) = dv4;
            *(float4*)(h1_out + base) = h14;
            *(float4*)(h0_out + base) = h04;
        }
    }
}

extern "C" void kernel_launch(void* const* d_in, const int* in_sizes, int n_in,
                              void* d_out, int out_size, void* d_ws, size_t ws_size,
                              hipStream_t stream) {
    const float* stim  = (const float*)d_in[0];
    const float* noise = (const float*)d_in[1];
    const float* a_p   = (const float*)d_in[2];
    const float* z_p   = (const float*)d_in[3];
    const float* g_p   = (const float*)d_in[4];
    const float* o_p   = (const float*)d_in[5];
    const float* b_p   = (const float*)d_in[6];
    float* outp = (float*)d_out;

    const int n_trials = in_sizes[0] / N_T;
    const int blocks = (n_trials + WAVES - 1) / WAVES;
    ddm_kernel<<<blocks, 256, 0, stream>>>(stim, noise, a_p, z_p, g_p, o_p, b_p,
                                           outp, n_trials);
}